// Round 5
// baseline (789.763 us; speedup 1.0000x reference)
//
#include <hip/hip_runtime.h>

#define NN 100000
#define NE 1600000
#define DD 128
#define BN_EPS 1e-5f

#define SCAN_CHUNK 512
#define SCAN_BLOCKS ((NN + SCAN_CHUNK - 1) / SCAN_CHUNK)  // 196
#define NBUCKETS ((NN + 127) / 128)                       // 782

typedef __attribute__((ext_vector_type(8))) short short8;
typedef __attribute__((ext_vector_type(4))) float floatx4;

__device__ __forceinline__ unsigned short f2bf(float f) {
    union { float f; unsigned u; } v; v.f = f;
    return (unsigned short)((v.u + 0x7FFFu + ((v.u >> 16) & 1u)) >> 16);
}
__device__ __forceinline__ float bf2f(unsigned short u) {
    union { unsigned u; float f; } v; v.u = ((unsigned)u) << 16;
    return v.f;
}

// ---------------------------------------------------------------------------
// Kernel 0: zero deg/stats; W1,W2 -> bf16 transposed [n][k]; optional h->bf16
// ---------------------------------------------------------------------------
__global__ __launch_bounds__(256) void prep_kernel(
    int* __restrict__ deg, float* __restrict__ stats,
    const float* __restrict__ W1, const float* __restrict__ W2,
    unsigned short* __restrict__ W1t, unsigned short* __restrict__ W2t,
    const float* __restrict__ h, unsigned short* __restrict__ hb, int do_hb)
{
    int tid0 = blockIdx.x * blockDim.x + threadIdx.x;
    int stride = gridDim.x * blockDim.x;
    for (int i = tid0; i < NN; i += stride) deg[i] = 0;
    if (tid0 < 2 * DD) stats[tid0] = 0.0f;
    for (int i = tid0; i < DD * DD; i += stride) {
        int n = i >> 7, k = i & 127;
        W1t[i] = f2bf(W1[k * DD + n]);
        W2t[i] = f2bf(W2[k * DD + n]);
    }
    if (do_hb) {
        const float4* h4 = (const float4*)h;
        ushort4* hb4 = (ushort4*)hb;
        for (int i = tid0; i < NN * (DD / 4); i += stride) {
            float4 v = h4[i];
            ushort4 o;
            o.x = f2bf(v.x); o.y = f2bf(v.y); o.z = f2bf(v.z); o.w = f2bf(v.w);
            hb4[i] = o;
        }
    }
}

// ---------------------------------------------------------------------------
// Kernel 1: histogram of dst
// ---------------------------------------------------------------------------
__global__ __launch_bounds__(256) void hist_kernel(
    const int* __restrict__ dst, int* __restrict__ deg)
{
    int e = blockIdx.x * blockDim.x + threadIdx.x;
    if (e < NE) atomicAdd(&deg[dst[e]], 1);
}

// ---------------------------------------------------------------------------
// Scan phase 1: per-block (512-elem chunk) sum of deg -> bsum
// ---------------------------------------------------------------------------
__global__ __launch_bounds__(256) void scan_bsum_kernel(
    const int* __restrict__ deg, int* __restrict__ bsum)
{
    __shared__ int sdata[256];
    int t = threadIdx.x;
    int j0 = blockIdx.x * SCAN_CHUNK + t * 2;
    int v = 0;
    if (j0 < NN) v += deg[j0];
    if (j0 + 1 < NN) v += deg[j0 + 1];
    sdata[t] = v;
    __syncthreads();
#pragma unroll
    for (int s = 128; s > 0; s >>= 1) {
        if (t < s) sdata[t] += sdata[t + s];
        __syncthreads();
    }
    if (t == 0) bsum[blockIdx.x] = sdata[0];
}

// ---------------------------------------------------------------------------
// Scan phase 2: single block exclusive-scans bsum in place
// ---------------------------------------------------------------------------
__global__ __launch_bounds__(256) void scan_spine_kernel(int* __restrict__ bsum)
{
    __shared__ int part[256];
    int t = threadIdx.x;
    int v = (t < SCAN_BLOCKS) ? bsum[t] : 0;
    part[t] = v;
    __syncthreads();
#pragma unroll
    for (int ofs = 1; ofs < 256; ofs <<= 1) {
        int u = (t >= ofs) ? part[t - ofs] : 0;
        __syncthreads();
        part[t] += u;
        __syncthreads();
    }
    if (t < SCAN_BLOCKS) bsum[t] = part[t] - v;
}

// ---------------------------------------------------------------------------
// Scan phase 3: block-level exclusive scan + spine offset -> off, bcur
// (bucket cursor bcur[b] = off[b*128] folded in)
// ---------------------------------------------------------------------------
__global__ __launch_bounds__(256) void scan_apply_kernel(
    const int* __restrict__ deg, const int* __restrict__ bsum,
    int* __restrict__ off, int* __restrict__ bcur)
{
    __shared__ int part[256];
    int t = threadIdx.x;
    int j0 = blockIdx.x * SCAN_CHUNK + t * 2;
    int d0 = (j0 < NN) ? deg[j0] : 0;
    int d1 = (j0 + 1 < NN) ? deg[j0 + 1] : 0;
    int ps = d0 + d1;
    part[t] = ps;
    __syncthreads();
#pragma unroll
    for (int ofs = 1; ofs < 256; ofs <<= 1) {
        int u = (t >= ofs) ? part[t - ofs] : 0;
        __syncthreads();
        part[t] += u;
        __syncthreads();
    }
    int excl = part[t] - ps + bsum[blockIdx.x];
    if (j0 < NN) {
        off[j0] = excl;
        if ((j0 & 127) == 0) bcur[j0 >> 7] = excl;
    }
    if (j0 + 1 < NN) off[j0 + 1] = excl + d0;
    if (blockIdx.x == 0 && t == 0) off[NN] = NE;
}

// ---------------------------------------------------------------------------
// Radix pass 1: append edges into their dst-bucket's CSR span (arbitrary
// order within bucket). Appends keep only ~782 write-frontier lines hot ->
// near-full line utilization. entry = (src<<7) | (dst&127), fits 24 bits.
// ---------------------------------------------------------------------------
__global__ __launch_bounds__(256) void radix_scatter_kernel(
    const int* __restrict__ src, const int* __restrict__ dst,
    int* __restrict__ bcur, int* __restrict__ stage)
{
    int e = blockIdx.x * blockDim.x + threadIdx.x;
    if (e < NE) {
        int d = dst[e];
        int pos = atomicAdd(&bcur[d >> 7], 1);
        stage[pos] = (src[e] << 7) | (d & 127);
    }
}

// ---------------------------------------------------------------------------
// Radix pass 2: one block per bucket; permute the bucket's staged entries
// into per-node CSR order via 128 LDS cursors. All writes land in the
// bucket's ~8KB contiguous window.
// ---------------------------------------------------------------------------
__global__ __launch_bounds__(256) void radix_permute_kernel(
    const int* __restrict__ off, const int* __restrict__ stage,
    int* __restrict__ src_sorted)
{
    __shared__ int cur[128];
    int b = blockIdx.x;
    int n0 = b << 7;
    int t = threadIdx.x;
    if (t < 128) {
        int n = n0 + t;
        cur[t] = (n < NN) ? off[n] : 0;
    }
    __syncthreads();
    int base = off[n0];
    int nend = (n0 + 128 < NN) ? (n0 + 128) : NN;
    int count = off[nend] - base;
    for (int i = t; i < count; i += 256) {
        int e = stage[base + i];
        int pos = atomicAdd(&cur[e & 127], 1);
        src_sorted[pos] = e >> 7;
    }
}

// ---------------------------------------------------------------------------
// Kernel 4a: gather-sum reading bf16 h copy, writing bf16 x
// ---------------------------------------------------------------------------
__global__ __launch_bounds__(256) void gather_bf16_kernel(
    const float* __restrict__ h, const unsigned short* __restrict__ hb,
    const float* __restrict__ eps, const int* __restrict__ off,
    const int* __restrict__ src_sorted, unsigned short* __restrict__ xb)
{
    int node = blockIdx.x * 8 + (threadIdx.x >> 5);
    if (node >= NN) return;
    int c4 = threadIdx.x & 31;
    const float s = 1.0f + eps[0];
    float4 hv = ((const float4*)h)[node * 32 + c4];
    float ax = s * hv.x, ay = s * hv.y, az = s * hv.z, aw = s * hv.w;
    const ushort4* hb4 = (const ushort4*)hb;
    int e = off[node], eend = off[node + 1];
    for (; e + 1 < eend; e += 2) {
        int s0 = src_sorted[e], s1 = src_sorted[e + 1];
        ushort4 v0 = hb4[s0 * 32 + c4];
        ushort4 v1 = hb4[s1 * 32 + c4];
        ax += bf2f(v0.x) + bf2f(v1.x);
        ay += bf2f(v0.y) + bf2f(v1.y);
        az += bf2f(v0.z) + bf2f(v1.z);
        aw += bf2f(v0.w) + bf2f(v1.w);
    }
    if (e < eend) {
        ushort4 v0 = hb4[src_sorted[e] * 32 + c4];
        ax += bf2f(v0.x); ay += bf2f(v0.y); az += bf2f(v0.z); aw += bf2f(v0.w);
    }
    ushort4 o;
    o.x = f2bf(ax); o.y = f2bf(ay); o.z = f2bf(az); o.w = f2bf(aw);
    ((ushort4*)xb)[node * 32 + c4] = o;
}

// ---------------------------------------------------------------------------
// Kernel 4b: gather-sum reading fp32 h (fallback if ws too small for hb)
// ---------------------------------------------------------------------------
__global__ __launch_bounds__(256) void gather_f32_kernel(
    const float* __restrict__ h, const float* __restrict__ eps,
    const int* __restrict__ off, const int* __restrict__ src_sorted,
    unsigned short* __restrict__ xb)
{
    int node = blockIdx.x * 8 + (threadIdx.x >> 5);
    if (node >= NN) return;
    int c4 = threadIdx.x & 31;
    const float4* h4 = (const float4*)h;
    const float s = 1.0f + eps[0];
    float4 hv = h4[node * 32 + c4];
    float ax = s * hv.x, ay = s * hv.y, az = s * hv.z, aw = s * hv.w;
    int e = off[node], eend = off[node + 1];
    for (; e + 1 < eend; e += 2) {
        float4 v0 = h4[src_sorted[e] * 32 + c4];
        float4 v1 = h4[src_sorted[e + 1] * 32 + c4];
        ax += v0.x + v1.x; ay += v0.y + v1.y;
        az += v0.z + v1.z; aw += v0.w + v1.w;
    }
    if (e < eend) {
        float4 v0 = h4[src_sorted[e] * 32 + c4];
        ax += v0.x; ay += v0.y; az += v0.z; aw += v0.w;
    }
    ushort4 o;
    o.x = f2bf(ax); o.y = f2bf(ay); o.z = f2bf(az); o.w = f2bf(aw);
    ((ushort4*)xb)[node * 32 + c4] = o;
}

// ---------------------------------------------------------------------------
// Kernel 5: bf16 MFMA GEMM: Y = (relu?)(X @ W + b). In-place safe.
// ---------------------------------------------------------------------------
template <bool RELU>
__global__ __launch_bounds__(256) void gemm_mfma_kernel(
    const unsigned short* __restrict__ X, const unsigned short* __restrict__ Wt,
    const float* __restrict__ bias, unsigned short* __restrict__ Y)
{
    extern __shared__ char smem[];
    unsigned short* wl = (unsigned short*)smem;            // [128][136] bf16
    unsigned short* xl = (unsigned short*)(smem + 34816);  // [64][136] bf16

    const int tid = threadIdx.x;
    const int r0 = blockIdx.x * 64;
    const int lane = tid & 63;
    const int wv = tid >> 6;
    const int m = lane & 15;
    const int hi = lane >> 4;

    const short8* Wt8 = (const short8*)Wt;
#pragma unroll
    for (int l = 0; l < 8; ++l) {
        int idx = tid + l * 256;
        int n = idx >> 4, c = idx & 15;
        *(short8*)&wl[n * 136 + c * 8] = Wt8[idx];
    }
    const short8* X8 = (const short8*)X;
#pragma unroll
    for (int l = 0; l < 4; ++l) {
        int idx = tid + l * 256;
        int row = idx >> 4, c = idx & 15;
        int g = r0 + row;
        short8 v = {0, 0, 0, 0, 0, 0, 0, 0};
        if (g < NN) v = X8[g * 16 + c];
        *(short8*)&xl[row * 136 + c * 8] = v;
    }
    __syncthreads();

    floatx4 acc[8];
#pragma unroll
    for (int i = 0; i < 8; ++i) acc[i] = (floatx4){0.f, 0.f, 0.f, 0.f};

#pragma unroll
    for (int kc = 0; kc < 4; ++kc) {
        short8 a = *(const short8*)&xl[(wv * 16 + m) * 136 + kc * 32 + hi * 8];
#pragma unroll
        for (int nt = 0; nt < 8; ++nt) {
            short8 b = *(const short8*)&wl[(nt * 16 + m) * 136 + kc * 32 + hi * 8];
            acc[nt] = __builtin_amdgcn_mfma_f32_16x16x32_bf16(a, b, acc[nt], 0, 0, 0);
        }
    }
    __syncthreads();

    unsigned short* cl = xl;  // reuse as C tile
#pragma unroll
    for (int nt = 0; nt < 8; ++nt) {
        float bv = bias[nt * 16 + m];
#pragma unroll
        for (int r = 0; r < 4; ++r) {
            float v = acc[nt][r] + bv;
            if (RELU) v = fmaxf(v, 0.f);
            cl[(wv * 16 + hi * 4 + r) * 136 + nt * 16 + m] = f2bf(v);
        }
    }
    __syncthreads();

#pragma unroll
    for (int l = 0; l < 4; ++l) {
        int idx = tid + l * 256;
        int row = idx >> 4, c = idx & 15;
        int g = r0 + row;
        if (g < NN)
            ((short8*)Y)[g * 16 + c] = *(const short8*)&cl[row * 136 + c * 8];
    }
}

// ---------------------------------------------------------------------------
// Kernel 6: per-column sum & sumsq of bf16 Y [N,128]
// ---------------------------------------------------------------------------
__global__ __launch_bounds__(256) void bn_stats_kernel(
    const unsigned short* __restrict__ Y, float* __restrict__ stats)
{
    const int cg = threadIdx.x & 31;
    const int rg = threadIdx.x >> 5;
    const ushort4* Y4 = (const ushort4*)Y;

    float4 s = make_float4(0.f, 0.f, 0.f, 0.f);
    float4 q = make_float4(0.f, 0.f, 0.f, 0.f);
    for (int r = blockIdx.x * 8 + rg; r < NN; r += gridDim.x * 8) {
        ushort4 u = Y4[r * 32 + cg];
        float vx = bf2f(u.x), vy = bf2f(u.y), vz = bf2f(u.z), vw = bf2f(u.w);
        s.x += vx; s.y += vy; s.z += vz; s.w += vw;
        q.x += vx * vx; q.y += vy * vy; q.z += vz * vz; q.w += vw * vw;
    }

    __shared__ float4 ls[8][32];
    __shared__ float4 lq[8][32];
    ls[rg][cg] = s;
    lq[rg][cg] = q;
    __syncthreads();
    if (rg == 0) {
        float4 ts = ls[0][cg], tq = lq[0][cg];
#pragma unroll
        for (int i = 1; i < 8; ++i) {
            float4 a = ls[i][cg], b = lq[i][cg];
            ts.x += a.x; ts.y += a.y; ts.z += a.z; ts.w += a.w;
            tq.x += b.x; tq.y += b.y; tq.z += b.z; tq.w += b.w;
        }
        int c = cg << 2;
        atomicAdd(&stats[c + 0], ts.x);
        atomicAdd(&stats[c + 1], ts.y);
        atomicAdd(&stats[c + 2], ts.z);
        atomicAdd(&stats[c + 3], ts.w);
        atomicAdd(&stats[DD + c + 0], tq.x);
        atomicAdd(&stats[DD + c + 1], tq.y);
        atomicAdd(&stats[DD + c + 2], tq.z);
        atomicAdd(&stats[DD + c + 3], tq.w);
    }
}

// ---------------------------------------------------------------------------
// Kernel 7: out = h + relu((Y - mean) * rsqrt(var+eps) * gamma + beta)
// ---------------------------------------------------------------------------
__global__ __launch_bounds__(256) void bn_final_kernel(
    const unsigned short* __restrict__ Y, const float* __restrict__ h,
    const float* __restrict__ gamma, const float* __restrict__ beta,
    const float* __restrict__ stats, float* __restrict__ out)
{
    const float invN = 1.0f / (float)NN;
    const ushort4* Y4 = (const ushort4*)Y;
    const float4* H4 = (const float4*)h;
    float4* O4 = (float4*)out;
    const int total = NN * (DD / 4);
    for (int i = blockIdx.x * blockDim.x + threadIdx.x; i < total;
         i += gridDim.x * blockDim.x) {
        int cg = i & 31;
        int c = cg << 2;
        ushort4 u = Y4[i];
        float4 hv = H4[i];
        float4 g = ((const float4*)gamma)[cg];
        float4 bt = ((const float4*)beta)[cg];

        float m0 = stats[c + 0] * invN, m1 = stats[c + 1] * invN;
        float m2 = stats[c + 2] * invN, m3 = stats[c + 3] * invN;
        float v0 = stats[DD + c + 0] * invN - m0 * m0;
        float v1 = stats[DD + c + 1] * invN - m1 * m1;
        float v2 = stats[DD + c + 2] * invN - m2 * m2;
        float v3 = stats[DD + c + 3] * invN - m3 * m3;

        float4 r;
        r.x = hv.x + fmaxf((bf2f(u.x) - m0) * rsqrtf(v0 + BN_EPS) * g.x + bt.x, 0.f);
        r.y = hv.y + fmaxf((bf2f(u.y) - m1) * rsqrtf(v1 + BN_EPS) * g.y + bt.y, 0.f);
        r.z = hv.z + fmaxf((bf2f(u.z) - m2) * rsqrtf(v2 + BN_EPS) * g.z + bt.z, 0.f);
        r.w = hv.w + fmaxf((bf2f(u.w) - m3) * rsqrtf(v3 + BN_EPS) * g.w + bt.w, 0.f);
        O4[i] = r;
    }
}

// ---------------------------------------------------------------------------
extern "C" void kernel_launch(void* const* d_in, const int* in_sizes, int n_in,
                              void* d_out, int out_size, void* d_ws, size_t ws_size,
                              hipStream_t stream)
{
    const float* h     = (const float*)d_in[0];
    const int*   src   = (const int*)d_in[1];
    const int*   dst   = (const int*)d_in[2];
    const float* eps   = (const float*)d_in[3];
    const float* W1    = (const float*)d_in[4];
    const float* b1    = (const float*)d_in[5];
    const float* W2    = (const float*)d_in[6];
    const float* b2    = (const float*)d_in[7];
    const float* gamma = (const float*)d_in[8];
    const float* beta  = (const float*)d_in[9];
    float* out = (float*)d_out;

    // workspace layout (16B-aligned segments). stage aliases xb: stage's
    // lifetime ends at radix_permute, xb's starts at gather.
    char* w = (char*)d_ws;
    size_t o = 0;
    int* deg        = (int*)(w + o); o += (size_t)NN * 4;
    int* off        = (int*)(w + o); o += (size_t)(NN + 4) * 4;
    int* bcur       = (int*)(w + o); o += (size_t)1024 * 4;
    float* stats    = (float*)(w + o); o += 256 * 4;
    int* bsum       = (int*)(w + o); o += 256 * 4;
    unsigned short* W1t = (unsigned short*)(w + o); o += (size_t)DD * DD * 2;
    unsigned short* W2t = (unsigned short*)(w + o); o += (size_t)DD * DD * 2;
    int* src_sorted = (int*)(w + o); o += (size_t)NE * 4;
    unsigned short* xb  = (unsigned short*)(w + o);
    int* stage      = (int*)xb;  // alias: NE*4 <= NN*DD*2
    o += (size_t)NN * DD * 2;
    unsigned short* hb  = (unsigned short*)(w + o); o += (size_t)NN * DD * 2;
    const int use_hb = (ws_size >= o) ? 1 : 0;  // launch-constant

    // 0. zero deg/stats, build bf16 transposed weights (+ bf16 h copy)
    prep_kernel<<<512, 256, 0, stream>>>(deg, stats, W1, W2, W1t, W2t, h, hb, use_hb);

    // 1. degree histogram
    hist_kernel<<<(NE + 255) / 256, 256, 0, stream>>>(dst, deg);

    // 2. parallel exclusive scan -> off (+ bucket cursors)
    scan_bsum_kernel<<<SCAN_BLOCKS, 256, 0, stream>>>(deg, bsum);
    scan_spine_kernel<<<1, 256, 0, stream>>>(bsum);
    scan_apply_kernel<<<SCAN_BLOCKS, 256, 0, stream>>>(deg, bsum, off, bcur);

    // 3. two-pass bucket radix -> src_sorted in CSR order
    radix_scatter_kernel<<<(NE + 255) / 256, 256, 0, stream>>>(src, dst, bcur, stage);
    radix_permute_kernel<<<NBUCKETS, 256, 0, stream>>>(off, stage, src_sorted);

    // 4. xb = bf16((1+eps)*h + neighbor-sum)   (overwrites stage — done with it)
    if (use_hb)
        gather_bf16_kernel<<<(NN + 7) / 8, 256, 0, stream>>>(h, hb, eps, off, src_sorted, xb);
    else
        gather_f32_kernel<<<(NN + 7) / 8, 256, 0, stream>>>(h, eps, off, src_sorted, xb);

    // 5/6. MLP via bf16 MFMA, in-place on xb
    int gemm_blocks = (NN + 63) / 64;  // 1563
    size_t gemm_lds = 34816 + 17408;   // 52224 B
    gemm_mfma_kernel<true><<<gemm_blocks, 256, gemm_lds, stream>>>(xb, W1t, b1, xb);
    gemm_mfma_kernel<false><<<gemm_blocks, 256, gemm_lds, stream>>>(xb, W2t, b2, xb);

    // 7. BN stats over bf16 y2
    bn_stats_kernel<<<512, 256, 0, stream>>>(xb, stats);

    // 8. out = h + relu(BN(y2))
    bn_final_kernel<<<1024, 256, 0, stream>>>(xb, h, gamma, beta, stats, out);
}

// Round 6
// 523.258 us; speedup vs baseline: 1.5093x; 1.5093x over previous
//
#include <hip/hip_runtime.h>

#define NN 100000
#define NE 1600000
#define DD 128
#define BN_EPS 1e-5f

#define SCAN_CHUNK 512
#define SCAN_BLOCKS ((NN + SCAN_CHUNK - 1) / SCAN_CHUNK)  // 196
#define NBUCKETS ((NN + 3) / 4)                           // 25000 (4 nodes each)
#define NWINDOWS ((NN + 127) / 128)                       // 782 permute windows

typedef __attribute__((ext_vector_type(8))) short short8;
typedef __attribute__((ext_vector_type(4))) float floatx4;

__device__ __forceinline__ unsigned short f2bf(float f) {
    union { float f; unsigned u; } v; v.f = f;
    return (unsigned short)((v.u + 0x7FFFu + ((v.u >> 16) & 1u)) >> 16);
}
__device__ __forceinline__ float bf2f(unsigned short u) {
    union { unsigned u; float f; } v; v.u = ((unsigned)u) << 16;
    return v.f;
}

// ---------------------------------------------------------------------------
// Kernel 0: zero deg/stats; W1,W2 -> bf16 transposed [n][k]; optional h->bf16
// ---------------------------------------------------------------------------
__global__ __launch_bounds__(256) void prep_kernel(
    int* __restrict__ deg, float* __restrict__ stats,
    const float* __restrict__ W1, const float* __restrict__ W2,
    unsigned short* __restrict__ W1t, unsigned short* __restrict__ W2t,
    const float* __restrict__ h, unsigned short* __restrict__ hb, int do_hb)
{
    int tid0 = blockIdx.x * blockDim.x + threadIdx.x;
    int stride = gridDim.x * blockDim.x;
    for (int i = tid0; i < NN; i += stride) deg[i] = 0;
    if (tid0 < 2 * DD) stats[tid0] = 0.0f;
    for (int i = tid0; i < DD * DD; i += stride) {
        int n = i >> 7, k = i & 127;
        W1t[i] = f2bf(W1[k * DD + n]);
        W2t[i] = f2bf(W2[k * DD + n]);
    }
    if (do_hb) {
        const float4* h4 = (const float4*)h;
        ushort4* hb4 = (ushort4*)hb;
        for (int i = tid0; i < NN * (DD / 4); i += stride) {
            float4 v = h4[i];
            ushort4 o;
            o.x = f2bf(v.x); o.y = f2bf(v.y); o.z = f2bf(v.z); o.w = f2bf(v.w);
            hb4[i] = o;
        }
    }
}

// ---------------------------------------------------------------------------
// Kernel 1: histogram of dst
// ---------------------------------------------------------------------------
__global__ __launch_bounds__(256) void hist_kernel(
    const int* __restrict__ dst, int* __restrict__ deg)
{
    int e = blockIdx.x * blockDim.x + threadIdx.x;
    if (e < NE) atomicAdd(&deg[dst[e]], 1);
}

// ---------------------------------------------------------------------------
// Scan phase 1: per-block (512-elem chunk) sum of deg -> bsum
// ---------------------------------------------------------------------------
__global__ __launch_bounds__(256) void scan_bsum_kernel(
    const int* __restrict__ deg, int* __restrict__ bsum)
{
    __shared__ int sdata[256];
    int t = threadIdx.x;
    int j0 = blockIdx.x * SCAN_CHUNK + t * 2;
    int v = 0;
    if (j0 < NN) v += deg[j0];
    if (j0 + 1 < NN) v += deg[j0 + 1];
    sdata[t] = v;
    __syncthreads();
#pragma unroll
    for (int s = 128; s > 0; s >>= 1) {
        if (t < s) sdata[t] += sdata[t + s];
        __syncthreads();
    }
    if (t == 0) bsum[blockIdx.x] = sdata[0];
}

// ---------------------------------------------------------------------------
// Scan phase 2: single block exclusive-scans bsum in place
// ---------------------------------------------------------------------------
__global__ __launch_bounds__(256) void scan_spine_kernel(int* __restrict__ bsum)
{
    __shared__ int part[256];
    int t = threadIdx.x;
    int v = (t < SCAN_BLOCKS) ? bsum[t] : 0;
    part[t] = v;
    __syncthreads();
#pragma unroll
    for (int ofs = 1; ofs < 256; ofs <<= 1) {
        int u = (t >= ofs) ? part[t - ofs] : 0;
        __syncthreads();
        part[t] += u;
        __syncthreads();
    }
    if (t < SCAN_BLOCKS) bsum[t] = part[t] - v;
}

// ---------------------------------------------------------------------------
// Scan phase 3: block-level exclusive scan + spine offset -> off, bcur
// (bucket cursor bcur[b] = off[b*4] folded in; 4-node buckets)
// ---------------------------------------------------------------------------
__global__ __launch_bounds__(256) void scan_apply_kernel(
    const int* __restrict__ deg, const int* __restrict__ bsum,
    int* __restrict__ off, int* __restrict__ bcur)
{
    __shared__ int part[256];
    int t = threadIdx.x;
    int j0 = blockIdx.x * SCAN_CHUNK + t * 2;
    int d0 = (j0 < NN) ? deg[j0] : 0;
    int d1 = (j0 + 1 < NN) ? deg[j0 + 1] : 0;
    int ps = d0 + d1;
    part[t] = ps;
    __syncthreads();
#pragma unroll
    for (int ofs = 1; ofs < 256; ofs <<= 1) {
        int u = (t >= ofs) ? part[t - ofs] : 0;
        __syncthreads();
        part[t] += u;
        __syncthreads();
    }
    int excl = part[t] - ps + bsum[blockIdx.x];
    if (j0 < NN) {
        off[j0] = excl;
        if ((j0 & 3) == 0) bcur[j0 >> 2] = excl;  // j0 even -> covers all mult-of-4
    }
    if (j0 + 1 < NN) off[j0 + 1] = excl + d0;
    if (blockIdx.x == 0 && t == 0) off[NN] = NE;
}

// ---------------------------------------------------------------------------
// Radix pass 1: append edges into their dst-bucket's CSR span. 25000 buckets
// of 4 nodes: low atomic contention (64 edges/counter) AND ~256B sequential
// append windows (low write amplification). entry = (src<<7) | (dst&127).
// ---------------------------------------------------------------------------
__global__ __launch_bounds__(256) void radix_scatter_kernel(
    const int* __restrict__ src, const int* __restrict__ dst,
    int* __restrict__ bcur, int* __restrict__ stage)
{
    int e = blockIdx.x * blockDim.x + threadIdx.x;
    if (e < NE) {
        int d = dst[e];
        int pos = atomicAdd(&bcur[d >> 2], 1);
        stage[pos] = (src[e] << 7) | (d & 127);
    }
}

// ---------------------------------------------------------------------------
// Radix pass 2: one block per 128-node window; permute the window's staged
// entries into per-node CSR order via 128 LDS cursors. 4-node buckets nest
// inside the window, so [off[n0], off[nend]) is still its contiguous span.
// ---------------------------------------------------------------------------
__global__ __launch_bounds__(256) void radix_permute_kernel(
    const int* __restrict__ off, const int* __restrict__ stage,
    int* __restrict__ src_sorted)
{
    __shared__ int cur[128];
    int b = blockIdx.x;
    int n0 = b << 7;
    int t = threadIdx.x;
    if (t < 128) {
        int n = n0 + t;
        cur[t] = (n < NN) ? off[n] : 0;
    }
    __syncthreads();
    int base = off[n0];
    int nend = (n0 + 128 < NN) ? (n0 + 128) : NN;
    int count = off[nend] - base;
    for (int i = t; i < count; i += 256) {
        int e = stage[base + i];
        int pos = atomicAdd(&cur[e & 127], 1);
        src_sorted[pos] = e >> 7;
    }
}

// ---------------------------------------------------------------------------
// Kernel 4a: gather-sum reading bf16 h copy, writing bf16 x
// ---------------------------------------------------------------------------
__global__ __launch_bounds__(256) void gather_bf16_kernel(
    const float* __restrict__ h, const unsigned short* __restrict__ hb,
    const float* __restrict__ eps, const int* __restrict__ off,
    const int* __restrict__ src_sorted, unsigned short* __restrict__ xb)
{
    int node = blockIdx.x * 8 + (threadIdx.x >> 5);
    if (node >= NN) return;
    int c4 = threadIdx.x & 31;
    const float s = 1.0f + eps[0];
    float4 hv = ((const float4*)h)[node * 32 + c4];
    float ax = s * hv.x, ay = s * hv.y, az = s * hv.z, aw = s * hv.w;
    const ushort4* hb4 = (const ushort4*)hb;
    int e = off[node], eend = off[node + 1];
    for (; e + 1 < eend; e += 2) {
        int s0 = src_sorted[e], s1 = src_sorted[e + 1];
        ushort4 v0 = hb4[s0 * 32 + c4];
        ushort4 v1 = hb4[s1 * 32 + c4];
        ax += bf2f(v0.x) + bf2f(v1.x);
        ay += bf2f(v0.y) + bf2f(v1.y);
        az += bf2f(v0.z) + bf2f(v1.z);
        aw += bf2f(v0.w) + bf2f(v1.w);
    }
    if (e < eend) {
        ushort4 v0 = hb4[src_sorted[e] * 32 + c4];
        ax += bf2f(v0.x); ay += bf2f(v0.y); az += bf2f(v0.z); aw += bf2f(v0.w);
    }
    ushort4 o;
    o.x = f2bf(ax); o.y = f2bf(ay); o.z = f2bf(az); o.w = f2bf(aw);
    ((ushort4*)xb)[node * 32 + c4] = o;
}

// ---------------------------------------------------------------------------
// Kernel 4b: gather-sum reading fp32 h (fallback if ws too small for hb)
// ---------------------------------------------------------------------------
__global__ __launch_bounds__(256) void gather_f32_kernel(
    const float* __restrict__ h, const float* __restrict__ eps,
    const int* __restrict__ off, const int* __restrict__ src_sorted,
    unsigned short* __restrict__ xb)
{
    int node = blockIdx.x * 8 + (threadIdx.x >> 5);
    if (node >= NN) return;
    int c4 = threadIdx.x & 31;
    const float4* h4 = (const float4*)h;
    const float s = 1.0f + eps[0];
    float4 hv = h4[node * 32 + c4];
    float ax = s * hv.x, ay = s * hv.y, az = s * hv.z, aw = s * hv.w;
    int e = off[node], eend = off[node + 1];
    for (; e + 1 < eend; e += 2) {
        float4 v0 = h4[src_sorted[e] * 32 + c4];
        float4 v1 = h4[src_sorted[e + 1] * 32 + c4];
        ax += v0.x + v1.x; ay += v0.y + v1.y;
        az += v0.z + v1.z; aw += v0.w + v1.w;
    }
    if (e < eend) {
        float4 v0 = h4[src_sorted[e] * 32 + c4];
        ax += v0.x; ay += v0.y; az += v0.z; aw += v0.w;
    }
    ushort4 o;
    o.x = f2bf(ax); o.y = f2bf(ay); o.z = f2bf(az); o.w = f2bf(aw);
    ((ushort4*)xb)[node * 32 + c4] = o;
}

// ---------------------------------------------------------------------------
// Kernel 5: bf16 MFMA GEMM: Y = (relu?)(X @ W + b). In-place safe.
// ---------------------------------------------------------------------------
template <bool RELU>
__global__ __launch_bounds__(256) void gemm_mfma_kernel(
    const unsigned short* __restrict__ X, const unsigned short* __restrict__ Wt,
    const float* __restrict__ bias, unsigned short* __restrict__ Y)
{
    extern __shared__ char smem[];
    unsigned short* wl = (unsigned short*)smem;            // [128][136] bf16
    unsigned short* xl = (unsigned short*)(smem + 34816);  // [64][136] bf16

    const int tid = threadIdx.x;
    const int r0 = blockIdx.x * 64;
    const int lane = tid & 63;
    const int wv = tid >> 6;
    const int m = lane & 15;
    const int hi = lane >> 4;

    const short8* Wt8 = (const short8*)Wt;
#pragma unroll
    for (int l = 0; l < 8; ++l) {
        int idx = tid + l * 256;
        int n = idx >> 4, c = idx & 15;
        *(short8*)&wl[n * 136 + c * 8] = Wt8[idx];
    }
    const short8* X8 = (const short8*)X;
#pragma unroll
    for (int l = 0; l < 4; ++l) {
        int idx = tid + l * 256;
        int row = idx >> 4, c = idx & 15;
        int g = r0 + row;
        short8 v = {0, 0, 0, 0, 0, 0, 0, 0};
        if (g < NN) v = X8[g * 16 + c];
        *(short8*)&xl[row * 136 + c * 8] = v;
    }
    __syncthreads();

    floatx4 acc[8];
#pragma unroll
    for (int i = 0; i < 8; ++i) acc[i] = (floatx4){0.f, 0.f, 0.f, 0.f};

#pragma unroll
    for (int kc = 0; kc < 4; ++kc) {
        short8 a = *(const short8*)&xl[(wv * 16 + m) * 136 + kc * 32 + hi * 8];
#pragma unroll
        for (int nt = 0; nt < 8; ++nt) {
            short8 b = *(const short8*)&wl[(nt * 16 + m) * 136 + kc * 32 + hi * 8];
            acc[nt] = __builtin_amdgcn_mfma_f32_16x16x32_bf16(a, b, acc[nt], 0, 0, 0);
        }
    }
    __syncthreads();

    unsigned short* cl = xl;  // reuse as C tile
#pragma unroll
    for (int nt = 0; nt < 8; ++nt) {
        float bv = bias[nt * 16 + m];
#pragma unroll
        for (int r = 0; r < 4; ++r) {
            float v = acc[nt][r] + bv;
            if (RELU) v = fmaxf(v, 0.f);
            cl[(wv * 16 + hi * 4 + r) * 136 + nt * 16 + m] = f2bf(v);
        }
    }
    __syncthreads();

#pragma unroll
    for (int l = 0; l < 4; ++l) {
        int idx = tid + l * 256;
        int row = idx >> 4, c = idx & 15;
        int g = r0 + row;
        if (g < NN)
            ((short8*)Y)[g * 16 + c] = *(const short8*)&cl[row * 136 + c * 8];
    }
}

// ---------------------------------------------------------------------------
// Kernel 6: per-column sum & sumsq of bf16 Y [N,128]
// ---------------------------------------------------------------------------
__global__ __launch_bounds__(256) void bn_stats_kernel(
    const unsigned short* __restrict__ Y, float* __restrict__ stats)
{
    const int cg = threadIdx.x & 31;
    const int rg = threadIdx.x >> 5;
    const ushort4* Y4 = (const ushort4*)Y;

    float4 s = make_float4(0.f, 0.f, 0.f, 0.f);
    float4 q = make_float4(0.f, 0.f, 0.f, 0.f);
    for (int r = blockIdx.x * 8 + rg; r < NN; r += gridDim.x * 8) {
        ushort4 u = Y4[r * 32 + cg];
        float vx = bf2f(u.x), vy = bf2f(u.y), vz = bf2f(u.z), vw = bf2f(u.w);
        s.x += vx; s.y += vy; s.z += vz; s.w += vw;
        q.x += vx * vx; q.y += vy * vy; q.z += vz * vz; q.w += vw * vw;
    }

    __shared__ float4 ls[8][32];
    __shared__ float4 lq[8][32];
    ls[rg][cg] = s;
    lq[rg][cg] = q;
    __syncthreads();
    if (rg == 0) {
        float4 ts = ls[0][cg], tq = lq[0][cg];
#pragma unroll
        for (int i = 1; i < 8; ++i) {
            float4 a = ls[i][cg], b = lq[i][cg];
            ts.x += a.x; ts.y += a.y; ts.z += a.z; ts.w += a.w;
            tq.x += b.x; tq.y += b.y; tq.z += b.z; tq.w += b.w;
        }
        int c = cg << 2;
        atomicAdd(&stats[c + 0], ts.x);
        atomicAdd(&stats[c + 1], ts.y);
        atomicAdd(&stats[c + 2], ts.z);
        atomicAdd(&stats[c + 3], ts.w);
        atomicAdd(&stats[DD + c + 0], tq.x);
        atomicAdd(&stats[DD + c + 1], tq.y);
        atomicAdd(&stats[DD + c + 2], tq.z);
        atomicAdd(&stats[DD + c + 3], tq.w);
    }
}

// ---------------------------------------------------------------------------
// Kernel 7: out = h + relu((Y - mean) * rsqrt(var+eps) * gamma + beta)
// ---------------------------------------------------------------------------
__global__ __launch_bounds__(256) void bn_final_kernel(
    const unsigned short* __restrict__ Y, const float* __restrict__ h,
    const float* __restrict__ gamma, const float* __restrict__ beta,
    const float* __restrict__ stats, float* __restrict__ out)
{
    const float invN = 1.0f / (float)NN;
    const ushort4* Y4 = (const ushort4*)Y;
    const float4* H4 = (const float4*)h;
    float4* O4 = (float4*)out;
    const int total = NN * (DD / 4);
    for (int i = blockIdx.x * blockDim.x + threadIdx.x; i < total;
         i += gridDim.x * blockDim.x) {
        int cg = i & 31;
        int c = cg << 2;
        ushort4 u = Y4[i];
        float4 hv = H4[i];
        float4 g = ((const float4*)gamma)[cg];
        float4 bt = ((const float4*)beta)[cg];

        float m0 = stats[c + 0] * invN, m1 = stats[c + 1] * invN;
        float m2 = stats[c + 2] * invN, m3 = stats[c + 3] * invN;
        float v0 = stats[DD + c + 0] * invN - m0 * m0;
        float v1 = stats[DD + c + 1] * invN - m1 * m1;
        float v2 = stats[DD + c + 2] * invN - m2 * m2;
        float v3 = stats[DD + c + 3] * invN - m3 * m3;

        float4 r;
        r.x = hv.x + fmaxf((bf2f(u.x) - m0) * rsqrtf(v0 + BN_EPS) * g.x + bt.x, 0.f);
        r.y = hv.y + fmaxf((bf2f(u.y) - m1) * rsqrtf(v1 + BN_EPS) * g.y + bt.y, 0.f);
        r.z = hv.z + fmaxf((bf2f(u.z) - m2) * rsqrtf(v2 + BN_EPS) * g.z + bt.z, 0.f);
        r.w = hv.w + fmaxf((bf2f(u.w) - m3) * rsqrtf(v3 + BN_EPS) * g.w + bt.w, 0.f);
        O4[i] = r;
    }
}

// ---------------------------------------------------------------------------
extern "C" void kernel_launch(void* const* d_in, const int* in_sizes, int n_in,
                              void* d_out, int out_size, void* d_ws, size_t ws_size,
                              hipStream_t stream)
{
    const float* h     = (const float*)d_in[0];
    const int*   src   = (const int*)d_in[1];
    const int*   dst   = (const int*)d_in[2];
    const float* eps   = (const float*)d_in[3];
    const float* W1    = (const float*)d_in[4];
    const float* b1    = (const float*)d_in[5];
    const float* W2    = (const float*)d_in[6];
    const float* b2    = (const float*)d_in[7];
    const float* gamma = (const float*)d_in[8];
    const float* beta  = (const float*)d_in[9];
    float* out = (float*)d_out;

    // workspace layout (16B-aligned segments). stage aliases xb.
    char* w = (char*)d_ws;
    size_t o = 0;
    int* deg        = (int*)(w + o); o += (size_t)NN * 4;
    int* off        = (int*)(w + o); o += (size_t)(NN + 4) * 4;
    int* bcur       = (int*)(w + o); o += (size_t)25024 * 4;   // NBUCKETS=25000
    float* stats    = (float*)(w + o); o += 256 * 4;
    int* bsum       = (int*)(w + o); o += 256 * 4;
    unsigned short* W1t = (unsigned short*)(w + o); o += (size_t)DD * DD * 2;
    unsigned short* W2t = (unsigned short*)(w + o); o += (size_t)DD * DD * 2;
    int* src_sorted = (int*)(w + o); o += (size_t)NE * 4;
    unsigned short* xb  = (unsigned short*)(w + o);
    int* stage      = (int*)xb;  // alias: NE*4 <= NN*DD*2
    o += (size_t)NN * DD * 2;
    unsigned short* hb  = (unsigned short*)(w + o); o += (size_t)NN * DD * 2;
    const int use_hb = (ws_size >= o) ? 1 : 0;  // launch-constant

    // 0. zero deg/stats, build bf16 transposed weights (+ bf16 h copy)
    prep_kernel<<<512, 256, 0, stream>>>(deg, stats, W1, W2, W1t, W2t, h, hb, use_hb);

    // 1. degree histogram
    hist_kernel<<<(NE + 255) / 256, 256, 0, stream>>>(dst, deg);

    // 2. parallel exclusive scan -> off (+ 4-node bucket cursors)
    scan_bsum_kernel<<<SCAN_BLOCKS, 256, 0, stream>>>(deg, bsum);
    scan_spine_kernel<<<1, 256, 0, stream>>>(bsum);
    scan_apply_kernel<<<SCAN_BLOCKS, 256, 0, stream>>>(deg, bsum, off, bcur);

    // 3. two-pass bucket radix -> src_sorted in CSR order
    radix_scatter_kernel<<<(NE + 255) / 256, 256, 0, stream>>>(src, dst, bcur, stage);
    radix_permute_kernel<<<NWINDOWS, 256, 0, stream>>>(off, stage, src_sorted);

    // 4. xb = bf16((1+eps)*h + neighbor-sum)   (overwrites stage — done with it)
    if (use_hb)
        gather_bf16_kernel<<<(NN + 7) / 8, 256, 0, stream>>>(h, hb, eps, off, src_sorted, xb);
    else
        gather_f32_kernel<<<(NN + 7) / 8, 256, 0, stream>>>(h, eps, off, src_sorted, xb);

    // 5/6. MLP via bf16 MFMA, in-place on xb
    int gemm_blocks = (NN + 63) / 64;  // 1563
    size_t gemm_lds = 34816 + 17408;   // 52224 B
    gemm_mfma_kernel<true><<<gemm_blocks, 256, gemm_lds, stream>>>(xb, W1t, b1, xb);
    gemm_mfma_kernel<false><<<gemm_blocks, 256, gemm_lds, stream>>>(xb, W2t, b2, xb);

    // 7. BN stats over bf16 y2
    bn_stats_kernel<<<512, 256, 0, stream>>>(xb, stats);

    // 8. out = h + relu(BN(y2))
    bn_final_kernel<<<1024, 256, 0, stream>>>(xb, h, gamma, beta, stats, out);
}

// Round 7
// 408.381 us; speedup vs baseline: 1.9339x; 1.2813x over previous
//
#include <hip/hip_runtime.h>

#define NN 100000
#define NE 1600000
#define DD 128
#define BN_EPS 1e-5f

#define NWIN 782                       // ceil(NN/128) 128-node windows
#define EPB 8192                       // edges per block (hist/scatter)
#define NBLK ((NE + EPB - 1) / EPB)    // 196
#define GM (NWIN * NBLK)               // 153272 (bin-major counters)
#define GM4 (GM / 4)                   // 38318 (GM divisible by 4)
#define G_BLOCKS ((GM4 + 255) / 256)   // 150

typedef __attribute__((ext_vector_type(8))) short short8;
typedef __attribute__((ext_vector_type(4))) float floatx4;

__device__ __forceinline__ unsigned short f2bf(float f) {
    union { float f; unsigned u; } v; v.f = f;
    return (unsigned short)((v.u + 0x7FFFu + ((v.u >> 16) & 1u)) >> 16);
}
__device__ __forceinline__ float bf2f(unsigned short u) {
    union { unsigned u; float f; } v; v.u = ((unsigned)u) << 16;
    return v.f;
}

// ---------------------------------------------------------------------------
// Kernel 0: zero stats; W1,W2 -> bf16 transposed [n][k]; optional h->bf16
// ---------------------------------------------------------------------------
__global__ __launch_bounds__(256) void prep_kernel(
    float* __restrict__ stats,
    const float* __restrict__ W1, const float* __restrict__ W2,
    unsigned short* __restrict__ W1t, unsigned short* __restrict__ W2t,
    const float* __restrict__ h, unsigned short* __restrict__ hb, int do_hb)
{
    int tid0 = blockIdx.x * blockDim.x + threadIdx.x;
    int stride = gridDim.x * blockDim.x;
    if (tid0 < 2 * DD) stats[tid0] = 0.0f;
    for (int i = tid0; i < DD * DD; i += stride) {
        int n = i >> 7, k = i & 127;
        W1t[i] = f2bf(W1[k * DD + n]);
        W2t[i] = f2bf(W2[k * DD + n]);
    }
    if (do_hb) {
        const float4* h4 = (const float4*)h;
        ushort4* hb4 = (ushort4*)hb;
        for (int i = tid0; i < NN * (DD / 4); i += stride) {
            float4 v = h4[i];
            ushort4 o;
            o.x = f2bf(v.x); o.y = f2bf(v.y); o.z = f2bf(v.z); o.w = f2bf(v.w);
            hb4[i] = o;
        }
    }
}

// ---------------------------------------------------------------------------
// P1: per-block window histogram. gbuf[bin*NBLK + blk] = count of this
// block's edges with dst in window bin. (bin-major for the scan)
// ---------------------------------------------------------------------------
__global__ __launch_bounds__(256) void whist_kernel(
    const int* __restrict__ dst, int* __restrict__ gbuf)
{
    __shared__ int bins[NWIN];
    int blk = blockIdx.x, t = threadIdx.x;
    for (int j = t; j < NWIN; j += 256) bins[j] = 0;
    __syncthreads();
    int base = blk * EPB;
    int cnt = min(EPB, NE - base);
    for (int i = t; i < cnt; i += 256)
        atomicAdd(&bins[dst[base + i] >> 7], 1);
    __syncthreads();
    for (int j = t; j < NWIN; j += 256) gbuf[j * NBLK + blk] = bins[j];
}

// ---------------------------------------------------------------------------
// P2a: per-block sums of gbuf chunks (1024 ints via int4)
// ---------------------------------------------------------------------------
__global__ __launch_bounds__(256) void gscan_bsum_kernel(
    const int* __restrict__ gbuf, int* __restrict__ gbsum)
{
    __shared__ int sd[256];
    int t = threadIdx.x;
    int idx4 = blockIdx.x * 256 + t;
    int s = 0;
    if (idx4 < GM4) {
        int4 v = ((const int4*)gbuf)[idx4];
        s = v.x + v.y + v.z + v.w;
    }
    sd[t] = s;
    __syncthreads();
#pragma unroll
    for (int k = 128; k > 0; k >>= 1) {
        if (t < k) sd[t] += sd[t + k];
        __syncthreads();
    }
    if (t == 0) gbsum[blockIdx.x] = sd[0];
}

// ---------------------------------------------------------------------------
// P2b: single block exclusive-scans gbsum[G_BLOCKS] in place
// ---------------------------------------------------------------------------
__global__ __launch_bounds__(256) void gscan_spine_kernel(int* __restrict__ gbsum)
{
    __shared__ int part[256];
    int t = threadIdx.x;
    int v = (t < G_BLOCKS) ? gbsum[t] : 0;
    part[t] = v;
    __syncthreads();
#pragma unroll
    for (int ofs = 1; ofs < 256; ofs <<= 1) {
        int u = (t >= ofs) ? part[t - ofs] : 0;
        __syncthreads();
        part[t] += u;
        __syncthreads();
    }
    if (t < G_BLOCKS) gbsum[t] = part[t] - v;
}

// ---------------------------------------------------------------------------
// P2c: exclusive prefix in place over gbuf (bin-major) + winoff at bin starts
// ---------------------------------------------------------------------------
__global__ __launch_bounds__(256) void gscan_apply_kernel(
    int* __restrict__ gbuf, const int* __restrict__ gbsum,
    int* __restrict__ winoff)
{
    __shared__ int part[256];
    int t = threadIdx.x;
    int idx4 = blockIdx.x * 256 + t;
    bool valid = idx4 < GM4;
    int4 v = make_int4(0, 0, 0, 0);
    if (valid) v = ((const int4*)gbuf)[idx4];
    int s = v.x + v.y + v.z + v.w;
    part[t] = s;
    __syncthreads();
#pragma unroll
    for (int ofs = 1; ofs < 256; ofs <<= 1) {
        int u = (t >= ofs) ? part[t - ofs] : 0;
        __syncthreads();
        part[t] += u;
        __syncthreads();
    }
    int excl = part[t] - s + gbsum[blockIdx.x];
    if (valid) {
        int p0 = excl, p1 = p0 + v.x, p2 = p1 + v.y, p3 = p2 + v.z;
        ((int4*)gbuf)[idx4] = make_int4(p0, p1, p2, p3);
        int gbase = idx4 * 4;
        int pr[4] = {p0, p1, p2, p3};
#pragma unroll
        for (int j = 0; j < 4; ++j) {
            int ge = gbase + j;
            if (ge % NBLK == 0) winoff[ge / NBLK] = pr[j];
        }
    }
    if (blockIdx.x == 0 && t == 0) winoff[NWIN] = NE;
}

// ---------------------------------------------------------------------------
// P3: block-local radix scatter. Each block owns contiguous runs per window
// -> stage lines written by (almost) one block only -> no cross-XCD line
// ping-pong. entry = (src<<7) | (dst&127).
// ---------------------------------------------------------------------------
__global__ __launch_bounds__(256) void wscatter_kernel(
    const int* __restrict__ src, const int* __restrict__ dst,
    const int* __restrict__ gcur, int* __restrict__ stage)
{
    __shared__ int cur[NWIN];
    int blk = blockIdx.x, t = threadIdx.x;
    for (int j = t; j < NWIN; j += 256) cur[j] = gcur[j * NBLK + blk];
    __syncthreads();
    int base = blk * EPB;
    int cnt = min(EPB, NE - base);
    for (int i = t; i < cnt; i += 256) {
        int e = base + i;
        int d = dst[e];
        int pos = atomicAdd(&cur[d >> 7], 1);
        stage[pos] = (src[e] << 7) | (d & 127);
    }
}

// ---------------------------------------------------------------------------
// P4: per-window permute into per-node CSR order. Derives per-node counts
// and offsets locally (no global node histogram/scan needed); writes off[].
// ---------------------------------------------------------------------------
__global__ __launch_bounds__(256) void wpermute_kernel(
    const int* __restrict__ winoff, const int* __restrict__ stage,
    int* __restrict__ src_sorted, int* __restrict__ off)
{
    __shared__ int cnt[128];
    __shared__ int part[128];
    __shared__ int cur[128];
    int b = blockIdx.x, t = threadIdx.x;
    if (t < 128) cnt[t] = 0;
    __syncthreads();
    int beg = winoff[b], end = winoff[b + 1];
    int n = end - beg;
    for (int i = t; i < n; i += 256)
        atomicAdd(&cnt[stage[beg + i] & 127], 1);
    __syncthreads();
    if (t < 128) part[t] = cnt[t];
    __syncthreads();
#pragma unroll
    for (int ofs = 1; ofs < 128; ofs <<= 1) {
        int u = (t < 128 && t >= ofs) ? part[t - ofs] : 0;
        __syncthreads();
        if (t < 128) part[t] += u;
        __syncthreads();
    }
    if (t < 128) {
        int excl = part[t] - cnt[t];
        cur[t] = beg + excl;
        int node = (b << 7) + t;
        if (node <= NN) off[node] = beg + excl;  // covers off[NN] in last window
    }
    __syncthreads();
    for (int i = t; i < n; i += 256) {
        int e = stage[beg + i];
        int pos = atomicAdd(&cur[e & 127], 1);
        src_sorted[pos] = e >> 7;
    }
}

// ---------------------------------------------------------------------------
// Kernel 4a: gather-sum reading bf16 h copy, writing bf16 x
// ---------------------------------------------------------------------------
__global__ __launch_bounds__(256) void gather_bf16_kernel(
    const float* __restrict__ h, const unsigned short* __restrict__ hb,
    const float* __restrict__ eps, const int* __restrict__ off,
    const int* __restrict__ src_sorted, unsigned short* __restrict__ xb)
{
    int node = blockIdx.x * 8 + (threadIdx.x >> 5);
    if (node >= NN) return;
    int c4 = threadIdx.x & 31;
    const float s = 1.0f + eps[0];
    float4 hv = ((const float4*)h)[node * 32 + c4];
    float ax = s * hv.x, ay = s * hv.y, az = s * hv.z, aw = s * hv.w;
    const ushort4* hb4 = (const ushort4*)hb;
    int e = off[node], eend = off[node + 1];
    for (; e + 1 < eend; e += 2) {
        int s0 = src_sorted[e], s1 = src_sorted[e + 1];
        ushort4 v0 = hb4[s0 * 32 + c4];
        ushort4 v1 = hb4[s1 * 32 + c4];
        ax += bf2f(v0.x) + bf2f(v1.x);
        ay += bf2f(v0.y) + bf2f(v1.y);
        az += bf2f(v0.z) + bf2f(v1.z);
        aw += bf2f(v0.w) + bf2f(v1.w);
    }
    if (e < eend) {
        ushort4 v0 = hb4[src_sorted[e] * 32 + c4];
        ax += bf2f(v0.x); ay += bf2f(v0.y); az += bf2f(v0.z); aw += bf2f(v0.w);
    }
    ushort4 o;
    o.x = f2bf(ax); o.y = f2bf(ay); o.z = f2bf(az); o.w = f2bf(aw);
    ((ushort4*)xb)[node * 32 + c4] = o;
}

// ---------------------------------------------------------------------------
// Kernel 4b: gather-sum reading fp32 h (fallback if ws too small for hb)
// ---------------------------------------------------------------------------
__global__ __launch_bounds__(256) void gather_f32_kernel(
    const float* __restrict__ h, const float* __restrict__ eps,
    const int* __restrict__ off, const int* __restrict__ src_sorted,
    unsigned short* __restrict__ xb)
{
    int node = blockIdx.x * 8 + (threadIdx.x >> 5);
    if (node >= NN) return;
    int c4 = threadIdx.x & 31;
    const float4* h4 = (const float4*)h;
    const float s = 1.0f + eps[0];
    float4 hv = h4[node * 32 + c4];
    float ax = s * hv.x, ay = s * hv.y, az = s * hv.z, aw = s * hv.w;
    int e = off[node], eend = off[node + 1];
    for (; e + 1 < eend; e += 2) {
        float4 v0 = h4[src_sorted[e] * 32 + c4];
        float4 v1 = h4[src_sorted[e + 1] * 32 + c4];
        ax += v0.x + v1.x; ay += v0.y + v1.y;
        az += v0.z + v1.z; aw += v0.w + v1.w;
    }
    if (e < eend) {
        float4 v0 = h4[src_sorted[e] * 32 + c4];
        ax += v0.x; ay += v0.y; az += v0.z; aw += v0.w;
    }
    ushort4 o;
    o.x = f2bf(ax); o.y = f2bf(ay); o.z = f2bf(az); o.w = f2bf(aw);
    ((ushort4*)xb)[node * 32 + c4] = o;
}

// ---------------------------------------------------------------------------
// Kernel 5: bf16 MFMA GEMM: Y = (relu?)(X @ W + b). In-place safe.
// ---------------------------------------------------------------------------
template <bool RELU>
__global__ __launch_bounds__(256) void gemm_mfma_kernel(
    const unsigned short* __restrict__ X, const unsigned short* __restrict__ Wt,
    const float* __restrict__ bias, unsigned short* __restrict__ Y)
{
    extern __shared__ char smem[];
    unsigned short* wl = (unsigned short*)smem;            // [128][136] bf16
    unsigned short* xl = (unsigned short*)(smem + 34816);  // [64][136] bf16

    const int tid = threadIdx.x;
    const int r0 = blockIdx.x * 64;
    const int lane = tid & 63;
    const int wv = tid >> 6;
    const int m = lane & 15;
    const int hi = lane >> 4;

    const short8* Wt8 = (const short8*)Wt;
#pragma unroll
    for (int l = 0; l < 8; ++l) {
        int idx = tid + l * 256;
        int n = idx >> 4, c = idx & 15;
        *(short8*)&wl[n * 136 + c * 8] = Wt8[idx];
    }
    const short8* X8 = (const short8*)X;
#pragma unroll
    for (int l = 0; l < 4; ++l) {
        int idx = tid + l * 256;
        int row = idx >> 4, c = idx & 15;
        int g = r0 + row;
        short8 v = {0, 0, 0, 0, 0, 0, 0, 0};
        if (g < NN) v = X8[g * 16 + c];
        *(short8*)&xl[row * 136 + c * 8] = v;
    }
    __syncthreads();

    floatx4 acc[8];
#pragma unroll
    for (int i = 0; i < 8; ++i) acc[i] = (floatx4){0.f, 0.f, 0.f, 0.f};

#pragma unroll
    for (int kc = 0; kc < 4; ++kc) {
        short8 a = *(const short8*)&xl[(wv * 16 + m) * 136 + kc * 32 + hi * 8];
#pragma unroll
        for (int nt = 0; nt < 8; ++nt) {
            short8 b = *(const short8*)&wl[(nt * 16 + m) * 136 + kc * 32 + hi * 8];
            acc[nt] = __builtin_amdgcn_mfma_f32_16x16x32_bf16(a, b, acc[nt], 0, 0, 0);
        }
    }
    __syncthreads();

    unsigned short* cl = xl;  // reuse as C tile
#pragma unroll
    for (int nt = 0; nt < 8; ++nt) {
        float bv = bias[nt * 16 + m];
#pragma unroll
        for (int r = 0; r < 4; ++r) {
            float v = acc[nt][r] + bv;
            if (RELU) v = fmaxf(v, 0.f);
            cl[(wv * 16 + hi * 4 + r) * 136 + nt * 16 + m] = f2bf(v);
        }
    }
    __syncthreads();

#pragma unroll
    for (int l = 0; l < 4; ++l) {
        int idx = tid + l * 256;
        int row = idx >> 4, c = idx & 15;
        int g = r0 + row;
        if (g < NN)
            ((short8*)Y)[g * 16 + c] = *(const short8*)&cl[row * 136 + c * 8];
    }
}

// ---------------------------------------------------------------------------
// Kernel 6: per-column sum & sumsq of bf16 Y [N,128]
// ---------------------------------------------------------------------------
__global__ __launch_bounds__(256) void bn_stats_kernel(
    const unsigned short* __restrict__ Y, float* __restrict__ stats)
{
    const int cg = threadIdx.x & 31;
    const int rg = threadIdx.x >> 5;
    const ushort4* Y4 = (const ushort4*)Y;

    float4 s = make_float4(0.f, 0.f, 0.f, 0.f);
    float4 q = make_float4(0.f, 0.f, 0.f, 0.f);
    for (int r = blockIdx.x * 8 + rg; r < NN; r += gridDim.x * 8) {
        ushort4 u = Y4[r * 32 + cg];
        float vx = bf2f(u.x), vy = bf2f(u.y), vz = bf2f(u.z), vw = bf2f(u.w);
        s.x += vx; s.y += vy; s.z += vz; s.w += vw;
        q.x += vx * vx; q.y += vy * vy; q.z += vz * vz; q.w += vw * vw;
    }

    __shared__ float4 ls[8][32];
    __shared__ float4 lq[8][32];
    ls[rg][cg] = s;
    lq[rg][cg] = q;
    __syncthreads();
    if (rg == 0) {
        float4 ts = ls[0][cg], tq = lq[0][cg];
#pragma unroll
        for (int i = 1; i < 8; ++i) {
            float4 a = ls[i][cg], b = lq[i][cg];
            ts.x += a.x; ts.y += a.y; ts.z += a.z; ts.w += a.w;
            tq.x += b.x; tq.y += b.y; tq.z += b.z; tq.w += b.w;
        }
        int c = cg << 2;
        atomicAdd(&stats[c + 0], ts.x);
        atomicAdd(&stats[c + 1], ts.y);
        atomicAdd(&stats[c + 2], ts.z);
        atomicAdd(&stats[c + 3], ts.w);
        atomicAdd(&stats[DD + c + 0], tq.x);
        atomicAdd(&stats[DD + c + 1], tq.y);
        atomicAdd(&stats[DD + c + 2], tq.z);
        atomicAdd(&stats[DD + c + 3], tq.w);
    }
}

// ---------------------------------------------------------------------------
// Kernel 7: out = h + relu((Y - mean) * rsqrt(var+eps) * gamma + beta)
// ---------------------------------------------------------------------------
__global__ __launch_bounds__(256) void bn_final_kernel(
    const unsigned short* __restrict__ Y, const float* __restrict__ h,
    const float* __restrict__ gamma, const float* __restrict__ beta,
    const float* __restrict__ stats, float* __restrict__ out)
{
    const float invN = 1.0f / (float)NN;
    const ushort4* Y4 = (const ushort4*)Y;
    const float4* H4 = (const float4*)h;
    float4* O4 = (float4*)out;
    const int total = NN * (DD / 4);
    for (int i = blockIdx.x * blockDim.x + threadIdx.x; i < total;
         i += gridDim.x * blockDim.x) {
        int cg = i & 31;
        int c = cg << 2;
        ushort4 u = Y4[i];
        float4 hv = H4[i];
        float4 g = ((const float4*)gamma)[cg];
        float4 bt = ((const float4*)beta)[cg];

        float m0 = stats[c + 0] * invN, m1 = stats[c + 1] * invN;
        float m2 = stats[c + 2] * invN, m3 = stats[c + 3] * invN;
        float v0 = stats[DD + c + 0] * invN - m0 * m0;
        float v1 = stats[DD + c + 1] * invN - m1 * m1;
        float v2 = stats[DD + c + 2] * invN - m2 * m2;
        float v3 = stats[DD + c + 3] * invN - m3 * m3;

        float4 r;
        r.x = hv.x + fmaxf((bf2f(u.x) - m0) * rsqrtf(v0 + BN_EPS) * g.x + bt.x, 0.f);
        r.y = hv.y + fmaxf((bf2f(u.y) - m1) * rsqrtf(v1 + BN_EPS) * g.y + bt.y, 0.f);
        r.z = hv.z + fmaxf((bf2f(u.z) - m2) * rsqrtf(v2 + BN_EPS) * g.z + bt.z, 0.f);
        r.w = hv.w + fmaxf((bf2f(u.w) - m3) * rsqrtf(v3 + BN_EPS) * g.w + bt.w, 0.f);
        O4[i] = r;
    }
}

// ---------------------------------------------------------------------------
extern "C" void kernel_launch(void* const* d_in, const int* in_sizes, int n_in,
                              void* d_out, int out_size, void* d_ws, size_t ws_size,
                              hipStream_t stream)
{
    const float* h     = (const float*)d_in[0];
    const int*   src   = (const int*)d_in[1];
    const int*   dst   = (const int*)d_in[2];
    const float* eps   = (const float*)d_in[3];
    const float* W1    = (const float*)d_in[4];
    const float* b1    = (const float*)d_in[5];
    const float* W2    = (const float*)d_in[6];
    const float* b2    = (const float*)d_in[7];
    const float* gamma = (const float*)d_in[8];
    const float* beta  = (const float*)d_in[9];
    float* out = (float*)d_out;

    // workspace layout (16B-aligned segments). stage aliases xb: stage's
    // lifetime ends at wpermute, xb's starts at gather.
    char* w = (char*)d_ws;
    size_t o = 0;
    int* gbuf       = (int*)(w + o); o += (size_t)GM * 4;        // 613088 (16|)
    int* winoff     = (int*)(w + o); o += (size_t)784 * 4;       // NWIN+1
    int* off        = (int*)(w + o); o += (size_t)(NN + 4) * 4;
    float* stats    = (float*)(w + o); o += 256 * 4;
    int* gbsum      = (int*)(w + o); o += 256 * 4;               // G_BLOCKS=150
    unsigned short* W1t = (unsigned short*)(w + o); o += (size_t)DD * DD * 2;
    unsigned short* W2t = (unsigned short*)(w + o); o += (size_t)DD * DD * 2;
    int* src_sorted = (int*)(w + o); o += (size_t)NE * 4;
    unsigned short* xb  = (unsigned short*)(w + o);
    int* stage      = (int*)xb;  // alias: NE*4 <= NN*DD*2
    o += (size_t)NN * DD * 2;
    unsigned short* hb  = (unsigned short*)(w + o); o += (size_t)NN * DD * 2;
    const int use_hb = (ws_size >= o) ? 1 : 0;  // launch-constant

    // 0. zero stats, build bf16 transposed weights (+ bf16 h copy)
    prep_kernel<<<512, 256, 0, stream>>>(stats, W1, W2, W1t, W2t, h, hb, use_hb);

    // 1. per-block window histograms (bin-major)
    whist_kernel<<<NBLK, 256, 0, stream>>>(dst, gbuf);

    // 2. exclusive scan over (bin, block) counters -> cursors + winoff
    gscan_bsum_kernel<<<G_BLOCKS, 256, 0, stream>>>(gbuf, gbsum);
    gscan_spine_kernel<<<1, 256, 0, stream>>>(gbsum);
    gscan_apply_kernel<<<G_BLOCKS, 256, 0, stream>>>(gbuf, gbsum, winoff);

    // 3. block-local radix scatter -> stage grouped by window
    wscatter_kernel<<<NBLK, 256, 0, stream>>>(src, dst, gbuf, stage);

    // 4. per-window permute -> src_sorted in CSR order + off[]
    wpermute_kernel<<<NWIN, 256, 0, stream>>>(winoff, stage, src_sorted, off);

    // 5. xb = bf16((1+eps)*h + neighbor-sum)   (overwrites stage — done with it)
    if (use_hb)
        gather_bf16_kernel<<<(NN + 7) / 8, 256, 0, stream>>>(h, hb, eps, off, src_sorted, xb);
    else
        gather_f32_kernel<<<(NN + 7) / 8, 256, 0, stream>>>(h, eps, off, src_sorted, xb);

    // 6/7. MLP via bf16 MFMA, in-place on xb
    int gemm_blocks = (NN + 63) / 64;  // 1563
    size_t gemm_lds = 34816 + 17408;   // 52224 B
    gemm_mfma_kernel<true><<<gemm_blocks, 256, gemm_lds, stream>>>(xb, W1t, b1, xb);
    gemm_mfma_kernel<false><<<gemm_blocks, 256, gemm_lds, stream>>>(xb, W2t, b2, xb);

    // 8. BN stats over bf16 y2
    bn_stats_kernel<<<512, 256, 0, stream>>>(xb, stats);

    // 9. out = h + relu(BN(y2))
    bn_final_kernel<<<1024, 256, 0, stream>>>(xb, h, gamma, beta, stats, out);
}